// Round 1
// baseline (434.409 us; speedup 1.0000x reference)
//
#include <hip/hip_runtime.h>

#define NB 4
#define NC 2
#define ND 160
#define NH 160
#define NW 160
#define NG 8

// mirror reflect t into [0, nm1], period 2*nm1 (scipy mode='mirror' /
// grid_sample reflection + align_corners=True)
__device__ __forceinline__ float reflect_mirror(float t, float nm1) {
    t = fabsf(t);
    if (t > nm1) {
        float p = 2.0f * nm1;
        t = t - p * floorf(t / p);   // fold into [0, p)
        if (t > nm1) t = p - t;
    }
    return t;
}

__global__ __launch_bounds__(256) void elastic_deform_kernel(
    const float* __restrict__ x,      // [B,C,D,H,W]
    const float* __restrict__ flow,   // [B,3,G,G,G]
    float* __restrict__ out)          // [B,C,D,H,W]
{
    const int HW  = NH * NW;
    const int DHW = ND * HW;
    int idx = blockIdx.x * blockDim.x + threadIdx.x;
    if (idx >= NB * DHW) return;

    int w = idx % NW;
    int t = idx / NW;
    int h = t % NH;
    t /= NH;
    int d = t % ND;
    int b = t / ND;

    // ---- upsample coarse flow at (d,h,w): trilinear, coords = i*(g-1)/(n-1)
    const float s = 7.0f / 159.0f;
    float cz = d * s, cy = h * s, cx = w * s;
    int iz0 = (int)cz, iy0 = (int)cy, ix0 = (int)cx;
    iz0 = min(iz0, NG - 1); iy0 = min(iy0, NG - 1); ix0 = min(ix0, NG - 1);
    float fz = cz - iz0, fy = cy - iy0, fx = cx - ix0;
    int iz1 = min(iz0 + 1, NG - 1);
    int iy1 = min(iy0 + 1, NG - 1);
    int ix1 = min(ix0 + 1, NG - 1);

    const float* fb = flow + b * 3 * NG * NG * NG;
    int o00 = (iz0 * NG + iy0) * NG;
    int o01 = (iz0 * NG + iy1) * NG;
    int o10 = (iz1 * NG + iy0) * NG;
    int o11 = (iz1 * NG + iy1) * NG;

    float up[3];
#pragma unroll
    for (int ch = 0; ch < 3; ++ch) {
        const float* f = fb + ch * (NG * NG * NG);
        float c000 = f[o00 + ix0], c001 = f[o00 + ix1];
        float c010 = f[o01 + ix0], c011 = f[o01 + ix1];
        float c100 = f[o10 + ix0], c101 = f[o10 + ix1];
        float c110 = f[o11 + ix0], c111 = f[o11 + ix1];
        float a00 = c000 + (c001 - c000) * fx;
        float a01 = c010 + (c011 - c010) * fx;
        float a10 = c100 + (c101 - c100) * fx;
        float a11 = c110 + (c111 - c110) * fx;
        float a0 = a00 + (a01 - a00) * fy;
        float a1 = a10 + (a11 - a10) * fy;
        up[ch] = a0 + (a1 - a0) * fz;
    }

    // ---- sample coordinates (unnormalize collapses to voxel + disp*79.5)
    float sx = (float)w + up[0] * 79.5f;
    float sy = (float)h + up[1] * 79.5f;
    float sz = (float)d + up[2] * 79.5f;

    sx = reflect_mirror(sx, (float)(NW - 1));
    sy = reflect_mirror(sy, (float)(NH - 1));
    sz = reflect_mirror(sz, (float)(ND - 1));

    int x0 = (int)sx, y0 = (int)sy, z0 = (int)sz;
    x0 = min(x0, NW - 1); y0 = min(y0, NH - 1); z0 = min(z0, ND - 1);
    float gx = sx - x0, gy = sy - y0, gz = sz - z0;
    int x1 = min(x0 + 1, NW - 1);
    int y1 = min(y0 + 1, NH - 1);
    int z1 = min(z0 + 1, ND - 1);

    // 8 corner offsets within one [D,H,W] volume (shared across channels)
    int p000 = (z0 * NH + y0) * NW + x0;
    int p001 = (z0 * NH + y0) * NW + x1;
    int p010 = (z0 * NH + y1) * NW + x0;
    int p011 = (z0 * NH + y1) * NW + x1;
    int p100 = (z1 * NH + y0) * NW + x0;
    int p101 = (z1 * NH + y0) * NW + x1;
    int p110 = (z1 * NH + y1) * NW + x0;
    int p111 = (z1 * NH + y1) * NW + x1;

    float wx0 = 1.0f - gx, wy0 = 1.0f - gy, wz0 = 1.0f - gz;
    float w000 = wz0 * wy0 * wx0;
    float w001 = wz0 * wy0 * gx;
    float w010 = wz0 * gy  * wx0;
    float w011 = wz0 * gy  * gx;
    float w100 = gz  * wy0 * wx0;
    float w101 = gz  * wy0 * gx;
    float w110 = gz  * gy  * wx0;
    float w111 = gz  * gy  * gx;

    int opos = (d * NH + h) * NW + w;
#pragma unroll
    for (int c = 0; c < NC; ++c) {
        const float* xv = x + ((size_t)(b * NC + c)) * DHW;
        float v = xv[p000] * w000 + xv[p001] * w001
                + xv[p010] * w010 + xv[p011] * w011
                + xv[p100] * w100 + xv[p101] * w101
                + xv[p110] * w110 + xv[p111] * w111;
        out[((size_t)(b * NC + c)) * DHW + opos] = v;
    }
}

extern "C" void kernel_launch(void* const* d_in, const int* in_sizes, int n_in,
                              void* d_out, int out_size, void* d_ws, size_t ws_size,
                              hipStream_t stream) {
    const float* x    = (const float*)d_in[0];
    const float* flow = (const float*)d_in[1];
    float* out = (float*)d_out;
    int total = NB * ND * NH * NW;   // one thread per (b,d,h,w), both channels
    int block = 256;
    int grid = (total + block - 1) / block;
    elastic_deform_kernel<<<grid, block, 0, stream>>>(x, flow, out);
}